// Round 7
// baseline (563.178 us; speedup 1.0000x reference)
//
#include <hip/hip_runtime.h>

#define DEV_INLINE __device__ __forceinline__

typedef __attribute__((ext_vector_type(8))) short bf16x8;
typedef __attribute__((ext_vector_type(4))) float floatx4;

DEV_INLINE unsigned fencode(float f) {
  unsigned u = __float_as_uint(f);
  return (u & 0x80000000u) ? ~u : (u | 0x80000000u);
}
DEV_INLINE float fdecode(unsigned k) {
  return __uint_as_float((k & 0x80000000u) ? (k ^ 0x80000000u) : ~k);
}

DEV_INLINE unsigned short bf16_rne(float x) {
  unsigned u = __float_as_uint(x);
  unsigned r = (u + 0x7FFFu + ((u >> 16) & 1u)) >> 16;
  return (unsigned short)r;
}
DEV_INLINE void bf16_split(float x, unsigned short& hi, unsigned short& lo) {
  hi = bf16_rne(x);
  float hf = __uint_as_float(((unsigned)hi) << 16);
  lo = bf16_rne(x - hf);
}
DEV_INLINE float bf2f(unsigned short u) {
  return __uint_as_float(((unsigned)u) << 16);
}

// ---------------- prep: transpose weights; bf16 hi/lo planes [N][K] -----------
__global__ __launch_bounds__(256)
void prep_kernel(const float* __restrict__ WA, const float* __restrict__ WB,
                 const float* __restrict__ WC, const float* __restrict__ WD,
                 const float* __restrict__ bA, const float* __restrict__ bB,
                 const float* __restrict__ bC, const float* __restrict__ bD,
                 const float* __restrict__ W2, const float* __restrict__ W3,
                 unsigned short* __restrict__ W1t_hi, unsigned short* __restrict__ W1t_lo,
                 unsigned short* __restrict__ W2t_hi, unsigned short* __restrict__ W2t_lo,
                 unsigned short* __restrict__ W3t_hi, unsigned short* __restrict__ W3t_lo,
                 float* __restrict__ biascat) {
  int i = blockIdx.x * 256 + threadIdx.x;
  if (i < 65536) {  // W1 planes: [z][j out][k in]
    int z = i >> 14, rem = i & 16383, j = rem >> 7, k = rem & 127;
    const float* W = (z == 0) ? WA : (z == 1) ? WB : (z == 2) ? WC : WD;
    unsigned short hi, lo;
    bf16_split(W[k * 128 + j], hi, lo);
    W1t_hi[i] = hi; W1t_lo[i] = lo;
  } else if (i < 196608) {  // W2t [256][512]
    int i2 = i - 65536, j = i2 >> 9, k = i2 & 511;
    unsigned short hi, lo;
    bf16_split(W2[k * 256 + j], hi, lo);
    W2t_hi[i2] = hi; W2t_lo[i2] = lo;
  } else if (i < 229376) {  // W3t [128][256]
    int i3 = i - 196608, j = i3 >> 8, k = i3 & 255;
    unsigned short hi, lo;
    bf16_split(W3[k * 128 + j], hi, lo);
    W3t_hi[i3] = hi; W3t_lo[i3] = lo;
  } else if (i < 229888) {
    int i4 = i - 229376, c = i4 >> 7, j = i4 & 127;
    const float* b = (c == 0) ? bA : (c == 1) ? bB : (c == 2) ? bC : bD;
    biascat[i4] = b[j];
  }
}

// ---------------- x -> bf16 cast ----------------------------------------------
__global__ __launch_bounds__(256)
void xcast_kernel(const float* __restrict__ x, unsigned short* __restrict__ xb, int total4) {
  int i = blockIdx.x * 256 + threadIdx.x;
  if (i >= total4) return;
  float4 v = ((const float4*)x)[i];
  ushort4 o;
  o.x = bf16_rne(v.x); o.y = bf16_rne(v.y); o.z = bf16_rne(v.z); o.w = bf16_rne(v.w);
  ((ushort4*)xb)[i] = o;
}

// ---------------- in-degree histogram ----------------------------------------
__global__ __launch_bounds__(256)
void hist_kernel(const int* __restrict__ ei, int* __restrict__ cnt, int E) {
  int e = blockIdx.x * 256 + threadIdx.x;
  if (e < E) atomicAdd(&cnt[ei[E + e]], 1);
}

// ---------------- 3-level exclusive scan -------------------------------------
__global__ __launch_bounds__(256)
void scan1_kernel(const int* __restrict__ cnt, int* __restrict__ local,
                  int* __restrict__ bsum, int n) {
  __shared__ int s[256];
  int tid = threadIdx.x;
  int i = blockIdx.x * 256 + tid;
  int v = (i < n) ? cnt[i] : 0;
  s[tid] = v;
  __syncthreads();
#pragma unroll
  for (int off = 1; off < 256; off <<= 1) {
    int t = (tid >= off) ? s[tid - off] : 0;
    __syncthreads();
    s[tid] += t;
    __syncthreads();
  }
  if (i < n) local[i] = s[tid] - v;
  if (tid == 255) bsum[blockIdx.x] = s[255];
}

__global__ __launch_bounds__(256)
void scan2_kernel(int* __restrict__ bsum, int nb) {
  __shared__ int s[256];
  int tid = threadIdx.x;
  int v = (tid < nb) ? bsum[tid] : 0;
  s[tid] = v;
  __syncthreads();
#pragma unroll
  for (int off = 1; off < 256; off <<= 1) {
    int t = (tid >= off) ? s[tid - off] : 0;
    __syncthreads();
    s[tid] += t;
    __syncthreads();
  }
  if (tid < nb) bsum[tid] = s[tid] - v;  // exclusive
}

__global__ __launch_bounds__(256)
void scan3_kernel(const int* __restrict__ local, const int* __restrict__ bsum,
                  int* __restrict__ rowptr, int* __restrict__ rowwork, int n, int E) {
  int i = blockIdx.x * 256 + threadIdx.x;
  if (i < n) {
    int rp = local[i] + bsum[blockIdx.x];
    rowptr[i] = rp;
    rowwork[i] = rp;
  }
  if (i == 0) rowptr[n] = E;
}

// ---------------- CSR fill (also writes src/dst per slot) ---------------------
__global__ __launch_bounds__(256)
void fill_kernel(const int* __restrict__ ei, int* __restrict__ rowwork,
                 int* __restrict__ csr, int* __restrict__ csr_src,
                 int* __restrict__ csr_dst, int E) {
  int e = blockIdx.x * 256 + threadIdx.x;
  if (e >= E) return;
  int d = ei[E + e];
  int pos = atomicAdd(&rowwork[d], 1);
  csr[pos] = e;
  csr_src[pos] = ei[e];
  csr_dst[pos] = d;
}

// ---------------- degrees from CSR (node-centric, fused rsqrt) ----------------
__global__ __launch_bounds__(256)
void degcsr_kernel(const int* __restrict__ rowptr, const int* __restrict__ csr,
                   const float* __restrict__ eattr, float* __restrict__ dis, int n) {
  int d = blockIdx.x * 256 + threadIdx.x;
  if (d >= n) return;
  int beg = rowptr[d], end = rowptr[d + 1];
  float s0 = 1.f, s1 = 1.f, s2 = 1.f, s3 = 1.f;  // self-loop weight 1
  for (int i = beg; i < end; ++i) {
    int e = csr[i];
    float4 w = ((const float4*)eattr)[e];
    s0 += w.x; s1 += w.y; s2 += w.z; s3 += w.w;
  }
  dis[d]         = 1.0f / sqrtf(s0);
  dis[n + d]     = 1.0f / sqrtf(s1);
  dis[2 * n + d] = 1.0f / sqrtf(s2);
  dis[3 * n + d] = 1.0f / sqrtf(s3);
  dis[4 * n + d] = 1.0f / sqrtf(1.0f + (float)(end - beg));
}

// ---------------- per-CSR-slot norms -------------------------------------------
__global__ __launch_bounds__(256)
void edgeprep_kernel(const int* __restrict__ csr, const int* __restrict__ csr_src,
                     const int* __restrict__ csr_dst, const float* __restrict__ eattr,
                     const float* __restrict__ dis, float4* __restrict__ norm4,
                     float* __restrict__ norm1, int n, int E) {
  int i = blockIdx.x * 256 + threadIdx.x;
  if (i >= E) return;
  int e = csr[i], s = csr_src[i], d = csr_dst[i];
  float4 w = ((const float4*)eattr)[e];
  float4 o;
  o.x = dis[s] * w.x * dis[d];
  o.y = dis[n + s] * w.y * dis[n + d];
  o.z = dis[2 * n + s] * w.z * dis[2 * n + d];
  o.w = dis[3 * n + s] * w.w * dis[3 * n + d];
  norm4[i] = o;
  norm1[i] = dis[4 * n + s] * dis[4 * n + d];
}

// ---------------- layer-1 aggregation on bf16 x; bf16 output -------------------
__global__ __launch_bounds__(256)
void agg4x_kernel(const unsigned short* __restrict__ xb,
                  unsigned short* __restrict__ xa,
                  const int* __restrict__ rowptr, const int* __restrict__ csr_src,
                  const float4* __restrict__ norm4, const float* __restrict__ dis,
                  int n, int npad) {
  int d = blockIdx.x * 4 + (threadIdx.x >> 6);
  if (d >= n) return;
  int t = threadIdx.x & 63;
  float dc0 = dis[d], dc1 = dis[n + d], dc2 = dis[2 * n + d], dc3 = dis[3 * n + d];
  const ushort2* x2 = (const ushort2*)xb;
  ushort2 xu = x2[(size_t)d * 64 + t];
  float xvx = bf2f(xu.x), xvy = bf2f(xu.y);
  float a0x = xvx * dc0 * dc0, a0y = xvy * dc0 * dc0;
  float a1x = xvx * dc1 * dc1, a1y = xvy * dc1 * dc1;
  float a2x = xvx * dc2 * dc2, a2y = xvy * dc2 * dc2;
  float a3x = xvx * dc3 * dc3, a3y = xvy * dc3 * dc3;
  int beg = rowptr[d], end = rowptr[d + 1];
  int i = beg;
  for (; i + 4 <= end; i += 4) {
    int s0 = csr_src[i], s1 = csr_src[i + 1], s2 = csr_src[i + 2], s3 = csr_src[i + 3];
    float4 m0 = norm4[i], m1 = norm4[i + 1], m2 = norm4[i + 2], m3 = norm4[i + 3];
    ushort2 u0 = x2[(size_t)s0 * 64 + t];
    ushort2 u1 = x2[(size_t)s1 * 64 + t];
    ushort2 u2 = x2[(size_t)s2 * 64 + t];
    ushort2 u3 = x2[(size_t)s3 * 64 + t];
    float h0x = bf2f(u0.x), h0y = bf2f(u0.y);
    float h1x = bf2f(u1.x), h1y = bf2f(u1.y);
    float h2x = bf2f(u2.x), h2y = bf2f(u2.y);
    float h3x = bf2f(u3.x), h3y = bf2f(u3.y);
    a0x += h0x * m0.x; a0y += h0y * m0.x;
    a1x += h0x * m0.y; a1y += h0y * m0.y;
    a2x += h0x * m0.z; a2y += h0y * m0.z;
    a3x += h0x * m0.w; a3y += h0y * m0.w;
    a0x += h1x * m1.x; a0y += h1y * m1.x;
    a1x += h1x * m1.y; a1y += h1y * m1.y;
    a2x += h1x * m1.z; a2y += h1y * m1.z;
    a3x += h1x * m1.w; a3y += h1y * m1.w;
    a0x += h2x * m2.x; a0y += h2y * m2.x;
    a1x += h2x * m2.y; a1y += h2y * m2.y;
    a2x += h2x * m2.z; a2y += h2y * m2.z;
    a3x += h2x * m2.w; a3y += h2y * m2.w;
    a0x += h3x * m3.x; a0y += h3y * m3.x;
    a1x += h3x * m3.y; a1y += h3y * m3.y;
    a2x += h3x * m3.z; a2y += h3y * m3.z;
    a3x += h3x * m3.w; a3y += h3y * m3.w;
  }
  for (; i < end; ++i) {
    int s = csr_src[i];
    float4 m = norm4[i];
    ushort2 u = x2[(size_t)s * 64 + t];
    float hx = bf2f(u.x), hy = bf2f(u.y);
    a0x += hx * m.x; a0y += hy * m.x;
    a1x += hx * m.y; a1y += hy * m.y;
    a2x += hx * m.z; a2y += hy * m.z;
    a3x += hx * m.w; a3y += hy * m.w;
  }
  size_t plane = (size_t)npad * 128;
  size_t base = (size_t)d * 128 + 2 * t;
  float vx[4] = {a0x, a1x, a2x, a3x};
  float vy[4] = {a0y, a1y, a2y, a3y};
#pragma unroll
  for (int z = 0; z < 4; ++z) {
    ushort2 ov; ov.x = bf16_rne(vx[z]); ov.y = bf16_rne(vy[z]);
    *(ushort2*)&xa[plane * z + base] = ov;
  }
}

// ---------------- streaming MFMA GEMM: LDS-resident B, barrier-free K-loop ----
// Block = 4 waves; wave handles SLABS x 16 rows x 32 cols. B tile (32 cols,
// K, hi+lo) loaded to LDS once. A slabs stream global->VGPR with 1-chunk
// prefetch; no __syncthreads in the K-loop (no vmcnt(0) drains).
// LDS layout unit u = ((kc*2+pl)*32 + c)*4 + q  (16B units).
template <int KC, int SLABS, bool BIASRELU>
DEV_INLINE void sgemm_body(const unsigned short* __restrict__ A,
                           const unsigned short* __restrict__ Bh,  // + n0*K
                           const unsigned short* __restrict__ Bl,
                           unsigned short* __restrict__ Cb, int ldc, int col0,
                           const float* __restrict__ bias, int M, int row0base) {
  constexpr int K = KC * 32;
  __shared__ __align__(16) unsigned short Bs[KC * 2 * 32 * 32];
  int tid = threadIdx.x;
  {
    constexpr int total = KC * 2 * 32 * 4;  // 16B units
#pragma unroll
    for (int u0 = 0; u0 < total; u0 += 256) {
      int u = u0 + tid;
      int q = u & 3, c = (u >> 2) & 31, pl = (u >> 7) & 1, kc = u >> 8;
      const unsigned short* src = (pl ? Bl : Bh) + c * K + kc * 32 + q * 8;
      *(uint4*)&Bs[u * 8] = *(const uint4*)src;
    }
  }
  __syncthreads();
  int w = tid >> 6, lane = tid & 63;
  int quad = lane >> 4, lrow = lane & 15;
  int rows0 = row0base + w * (SLABS * 16);

  floatx4 acc[SLABS][2];
#pragma unroll
  for (int s = 0; s < SLABS; ++s) {
    acc[s][0] = {0.f, 0.f, 0.f, 0.f};
    acc[s][1] = {0.f, 0.f, 0.f, 0.f};
  }
  const unsigned short* aptr[SLABS];
#pragma unroll
  for (int s = 0; s < SLABS; ++s)
    aptr[s] = A + (size_t)(rows0 + s * 16 + lrow) * K + quad * 8;

  bf16x8 acur[SLABS];
#pragma unroll
  for (int s = 0; s < SLABS; ++s) acur[s] = *(const bf16x8*)(aptr[s]);

#pragma unroll
  for (int kc = 0; kc < KC; ++kc) {
    bf16x8 anxt[SLABS];
    if (kc + 1 < KC) {
#pragma unroll
      for (int s = 0; s < SLABS; ++s)
        anxt[s] = *(const bf16x8*)(aptr[s] + (kc + 1) * 32);
    }
#pragma unroll
    for (int nf = 0; nf < 2; ++nf) {
      int boff = (((kc * 2) * 32 + nf * 16 + lrow) * 4 + quad) * 8;
      bf16x8 bh = *(const bf16x8*)&Bs[boff];
      bf16x8 bl = *(const bf16x8*)&Bs[boff + 32 * 32];  // pl stride = 32*4*8 ushorts
#pragma unroll
      for (int s = 0; s < SLABS; ++s) {
        acc[s][nf] = __builtin_amdgcn_mfma_f32_16x16x32_bf16(acur[s], bh, acc[s][nf], 0, 0, 0);
        acc[s][nf] = __builtin_amdgcn_mfma_f32_16x16x32_bf16(acur[s], bl, acc[s][nf], 0, 0, 0);
      }
    }
    if (kc + 1 < KC) {
#pragma unroll
      for (int s = 0; s < SLABS; ++s) acur[s] = anxt[s];
    }
  }
  // epilogue: C/D layout col=lane&15, row=quad*4+reg
#pragma unroll
  for (int s = 0; s < SLABS; ++s) {
#pragma unroll
    for (int nf = 0; nf < 2; ++nf) {
      int colL = col0 + nf * 16 + lrow;
#pragma unroll
      for (int r = 0; r < 4; ++r) {
        int row = rows0 + s * 16 + quad * 4 + r;
        if (row < M) {
          float v = acc[s][nf][r];
          if (BIASRELU) v = fmaxf(v + bias[nf * 16 + lrow], 0.0f);
          Cb[(size_t)row * ldc + colL] = bf16_rne(v);
        }
      }
    }
  }
}

// layer 1: grid (npad/512, 16): y = z*4 + coltile
__global__ __launch_bounds__(256)
void sgemm_l1(const unsigned short* __restrict__ xa,
              const unsigned short* __restrict__ W1t_hi,
              const unsigned short* __restrict__ W1t_lo,
              const float* __restrict__ biascat,
              unsigned short* __restrict__ h1, int M, int npad) {
  int z = blockIdx.y >> 2, ct = blockIdx.y & 3;
  int bofs = z * 16384 + ct * 32 * 128;
  sgemm_body<4, 8, true>(xa + (size_t)z * npad * 128, W1t_hi + bofs, W1t_lo + bofs,
                         h1, 512, z * 128 + ct * 32, biascat + z * 128 + ct * 32,
                         M, blockIdx.x * 512);
}

// layer 2: grid (npad/512, 8)
__global__ __launch_bounds__(256)
void sgemm_l2(const unsigned short* __restrict__ h1,
              const unsigned short* __restrict__ W2t_hi,
              const unsigned short* __restrict__ W2t_lo,
              unsigned short* __restrict__ h2pre, int M) {
  int n0 = blockIdx.y * 32;
  sgemm_body<16, 8, false>(h1, W2t_hi + n0 * 512, W2t_lo + n0 * 512,
                           h2pre, 256, n0, nullptr, M, blockIdx.x * 512);
}

// layer 3: grid (npad/256, 4)
__global__ __launch_bounds__(256)
void sgemm_l3(const unsigned short* __restrict__ h2,
              const unsigned short* __restrict__ W3t_hi,
              const unsigned short* __restrict__ W3t_lo,
              unsigned short* __restrict__ h3pre, int M) {
  int n0 = blockIdx.y * 32;
  sgemm_body<8, 4, false>(h2, W3t_hi + n0 * 256, W3t_lo + n0 * 256,
                          h3pre, 128, n0, nullptr, M, blockIdx.x * 256);
}

// ---------------- layers 2/3 aggregation: bf16 gather, 4-edge unroll ----------
template <int VEC, bool RELU, int OMODE>
__global__ __launch_bounds__(256)
void agg1_kernel(const unsigned short* __restrict__ hb, float* __restrict__ out,
                 unsigned short* __restrict__ ob,
                 const int* __restrict__ rowptr, const int* __restrict__ csr_src,
                 const float* __restrict__ norm1, const float* __restrict__ dis1,
                 const float* __restrict__ bias, int n) {
  constexpr int DOUT = VEC * 64;
  int d = blockIdx.x * 4 + (threadIdx.x >> 6);
  if (d >= n) return;
  int t = threadIdx.x & 63;
  float dd = dis1[d];
  float acc[VEC];
  {
    float sw = dd * dd;
#pragma unroll
    for (int k = 0; k < VEC; ++k) acc[k] = bf2f(hb[(size_t)d * DOUT + t * VEC + k]) * sw;
  }
  int beg = rowptr[d], end = rowptr[d + 1];
  int i = beg;
  for (; i + 4 <= end; i += 4) {
    int s0 = csr_src[i], s1 = csr_src[i + 1], s2 = csr_src[i + 2], s3 = csr_src[i + 3];
    float m0 = norm1[i], m1 = norm1[i + 1], m2 = norm1[i + 2], m3 = norm1[i + 3];
    if (VEC == 4) {
      ushort4 u0 = *(const ushort4*)&hb[(size_t)s0 * DOUT + t * 4];
      ushort4 u1 = *(const ushort4*)&hb[(size_t)s1 * DOUT + t * 4];
      ushort4 u2 = *(const ushort4*)&hb[(size_t)s2 * DOUT + t * 4];
      ushort4 u3 = *(const ushort4*)&hb[(size_t)s3 * DOUT + t * 4];
      acc[0] += bf2f(u0.x) * m0; acc[1] += bf2f(u0.y) * m0;
      acc[2 % VEC] += bf2f(u0.z) * m0; acc[3 % VEC] += bf2f(u0.w) * m0;
      acc[0] += bf2f(u1.x) * m1; acc[1] += bf2f(u1.y) * m1;
      acc[2 % VEC] += bf2f(u1.z) * m1; acc[3 % VEC] += bf2f(u1.w) * m1;
      acc[0] += bf2f(u2.x) * m2; acc[1] += bf2f(u2.y) * m2;
      acc[2 % VEC] += bf2f(u2.z) * m2; acc[3 % VEC] += bf2f(u2.w) * m2;
      acc[0] += bf2f(u3.x) * m3; acc[1] += bf2f(u3.y) * m3;
      acc[2 % VEC] += bf2f(u3.z) * m3; acc[3 % VEC] += bf2f(u3.w) * m3;
    } else {
      ushort2 u0 = *(const ushort2*)&hb[(size_t)s0 * DOUT + t * 2];
      ushort2 u1 = *(const ushort2*)&hb[(size_t)s1 * DOUT + t * 2];
      ushort2 u2 = *(const ushort2*)&hb[(size_t)s2 * DOUT + t * 2];
      ushort2 u3 = *(const ushort2*)&hb[(size_t)s3 * DOUT + t * 2];
      acc[0] += bf2f(u0.x) * m0; acc[1 % VEC] += bf2f(u0.y) * m0;
      acc[0] += bf2f(u1.x) * m1; acc[1 % VEC] += bf2f(u1.y) * m1;
      acc[0] += bf2f(u2.x) * m2; acc[1 % VEC] += bf2f(u2.y) * m2;
      acc[0] += bf2f(u3.x) * m3; acc[1 % VEC] += bf2f(u3.y) * m3;
    }
  }
  for (; i < end; ++i) {
    int s = csr_src[i];
    float nrm = norm1[i];
    if (VEC == 4) {
      ushort4 u = *(const ushort4*)&hb[(size_t)s * DOUT + t * 4];
      acc[0] += bf2f(u.x) * nrm; acc[1] += bf2f(u.y) * nrm;
      acc[2 % VEC] += bf2f(u.z) * nrm; acc[3 % VEC] += bf2f(u.w) * nrm;
    } else {
      ushort2 u = *(const ushort2*)&hb[(size_t)s * DOUT + t * 2];
      acc[0] += bf2f(u.x) * nrm; acc[1 % VEC] += bf2f(u.y) * nrm;
    }
  }
#pragma unroll
  for (int k = 0; k < VEC; ++k) {
    float r = acc[k] + bias[t * VEC + k];
    if (RELU) r = fmaxf(r, 0.0f);
    if (OMODE == 1) {
      ob[(size_t)d * DOUT + t * VEC + k] = bf16_rne(r);
    } else {
      out[(size_t)d * DOUT + t * VEC + k] = r;
    }
  }
}

// ---------------- pooling: per-graph sum + max (encoded uint) -----------------
__global__ __launch_bounds__(128)
void pool_kernel(const float* __restrict__ h3, const int* __restrict__ batch,
                 float* __restrict__ gsum, unsigned* __restrict__ gmax, int n) {
  int c = threadIdx.x;
  int start = blockIdx.x * 32;
  int end = min(start + 32, n);
  int curg = -1;
  float s = 0.0f, m = -3.402823466e38f;
  for (int i = start; i < end; ++i) {
    int g = batch[i];
    if (g != curg) {
      if (curg >= 0) {
        atomicAdd(&gsum[curg * 128 + c], s);
        atomicMax(&gmax[curg * 128 + c], fencode(m));
      }
      curg = g; s = 0.0f; m = -3.402823466e38f;
    }
    float v = h3[(size_t)i * 128 + c];
    s += v;
    m = fmaxf(m, v);
  }
  if (curg >= 0) {
    atomicAdd(&gsum[curg * 128 + c], s);
    atomicMax(&gmax[curg * 128 + c], fencode(m));
  }
}

// ---------------- final MLP; per-graph counts via binary search ---------------
__global__ __launch_bounds__(512)
void mlp_kernel(const float* __restrict__ gsum, const unsigned* __restrict__ gmax,
                const int* __restrict__ batch, int n, const float* __restrict__ Wm1,
                const float* __restrict__ bm1, const float* __restrict__ Wm2,
                const float* __restrict__ bm2, float* __restrict__ out) {
  __shared__ float hid[64][8];
  int t = threadIdx.x;
  int gi = t >> 3, u = t & 7;
  auto lb = [&](int key) {
    int lo = 0, hi = n;
    while (lo < hi) {
      int mid = (lo + hi) >> 1;
      if (batch[mid] < key) lo = mid + 1; else hi = mid;
    }
    return lo;
  };
  int cnt = lb(gi + 1) - lb(gi);
  float inv = 1.0f / fmaxf((float)cnt, 1.0f);
  float s = bm1[u];
  for (int k = 0; k < 128; ++k) {
    float mean = gsum[gi * 128 + k] * inv;
    s += mean * Wm1[k * 8 + u];
  }
  for (int k = 0; k < 128; ++k) {
    float mx = (cnt > 0) ? fdecode(gmax[gi * 128 + k]) : 0.0f;
    s += mx * Wm1[(128 + k) * 8 + u];
  }
  hid[gi][u] = fmaxf(s, 0.0f);
  __syncthreads();
  if (t < 128) {
    int g2 = t >> 1, o = t & 1;
    float s2 = bm2[o];
#pragma unroll
    for (int uu = 0; uu < 8; ++uu) s2 += hid[g2][uu] * Wm2[uu * 2 + o];
    out[g2 * 2 + o] = s2;
  }
}

extern "C" void kernel_launch(void* const* d_in, const int* in_sizes, int n_in,
                              void* d_out, int out_size, void* d_ws, size_t ws_size,
                              hipStream_t stream) {
  const float* x     = (const float*)d_in[0];
  const int*   ei    = (const int*)d_in[1];
  const float* eattr = (const float*)d_in[2];
  const int*   batch = (const int*)d_in[3];
  const float* W1A = (const float*)d_in[4],  *b1A = (const float*)d_in[5];
  const float* W1B = (const float*)d_in[6],  *b1B = (const float*)d_in[7];
  const float* W1C = (const float*)d_in[8],  *b1C = (const float*)d_in[9];
  const float* W1D = (const float*)d_in[10], *b1D = (const float*)d_in[11];
  const float* W2  = (const float*)d_in[12], *b2  = (const float*)d_in[13];
  const float* W3  = (const float*)d_in[14], *b3  = (const float*)d_in[15];
  const float* Wm1 = (const float*)d_in[16], *bm1 = (const float*)d_in[17];
  const float* Wm2 = (const float*)d_in[18], *bm2 = (const float*)d_in[19];
  float* out = (float*)d_out;

  const int n = in_sizes[0] / 128;
  const int E = in_sizes[1] / 2;
  const int npad = (n + 511) & ~511;  // multiple of 512 for streaming GEMM tiles

  char* ws = (char*)d_ws;
  size_t off = 0;
  auto alloc = [&](size_t bytes) -> void* {
    void* p = ws + off;
    off += (bytes + 255) & ~(size_t)255;
    return p;
  };

  float*    dis     = (float*)alloc((size_t)5 * n * 4);
  int*      rowptr  = (int*)alloc(((size_t)n + 1) * 4);
  int*      rowwork = (int*)alloc((size_t)n * 4);
  int*      local   = (int*)alloc((size_t)n * 4);
  int*      bsum    = (int*)alloc(256 * 4);
  // ---- zero block start ----
  size_t zoff = off;
  int*      cnt     = (int*)alloc((size_t)n * 4);
  float*    gsum    = (float*)alloc(64 * 128 * 4);
  unsigned* gmax    = (unsigned*)alloc(64 * 128 * 4);
  size_t zbytes = off - zoff;
  // ---- zero block end ----
  int*      csr     = (int*)alloc((size_t)E * 4);
  int*      csr_src = (int*)alloc((size_t)E * 4);
  int*      csr_dst = (int*)alloc((size_t)E * 4);
  float4*   norm4   = (float4*)alloc((size_t)E * 16);
  float*    norm1   = (float*)alloc((size_t)E * 4);
  unsigned short* W1t_hi = (unsigned short*)alloc(65536 * 2);
  unsigned short* W1t_lo = (unsigned short*)alloc(65536 * 2);
  unsigned short* W2t_hi = (unsigned short*)alloc(131072 * 2);
  unsigned short* W2t_lo = (unsigned short*)alloc(131072 * 2);
  unsigned short* W3t_hi = (unsigned short*)alloc(32768 * 2);
  unsigned short* W3t_lo = (unsigned short*)alloc(32768 * 2);
  float*    biascat = (float*)alloc(512 * 4);
  unsigned short* xb   = (unsigned short*)alloc((size_t)npad * 128 * 2);
  unsigned short* bufA = (unsigned short*)alloc((size_t)npad * 512 * 2);  // xa / h2pre / h3pre
  unsigned short* bufB = (unsigned short*)alloc((size_t)npad * 512 * 2);  // h1 / h2+h3
  alloc(4096);  // guard pad

  unsigned short* xa      = bufA;                     // 4 planes [npad,128] bf16
  unsigned short* h1      = bufB;                     // [npad,512] bf16
  unsigned short* h2pre_b = bufA;                     // [npad,256] bf16 (xa dead)
  unsigned short* h2      = bufB;                     // [npad,256] bf16 (h1 dead after gemm_l2)
  unsigned short* h3pre_b = bufA;                     // [npad,128] bf16 (h2pre dead)
  float*          h3      = (float*)(bufB + (size_t)npad * 256);  // [npad,128] fp32

  hipMemsetAsync(ws + zoff, 0, zbytes, stream);

  prep_kernel<<<(229888 + 255) / 256, 256, 0, stream>>>(
      W1A, W1B, W1C, W1D, b1A, b1B, b1C, b1D, W2, W3,
      W1t_hi, W1t_lo, W2t_hi, W2t_lo, W3t_hi, W3t_lo, biascat);
  xcast_kernel<<<((n * 32) + 255) / 256, 256, 0, stream>>>(x, xb, n * 32);

  int nb = (n + 255) / 256;
  hist_kernel<<<(E + 255) / 256, 256, 0, stream>>>(ei, cnt, E);
  scan1_kernel<<<nb, 256, 0, stream>>>(cnt, local, bsum, n);
  scan2_kernel<<<1, 256, 0, stream>>>(bsum, nb);
  scan3_kernel<<<nb, 256, 0, stream>>>(local, bsum, rowptr, rowwork, n, E);
  fill_kernel<<<(E + 255) / 256, 256, 0, stream>>>(ei, rowwork, csr, csr_src, csr_dst, E);
  degcsr_kernel<<<(n + 255) / 256, 256, 0, stream>>>(rowptr, csr, eattr, dis, n);
  edgeprep_kernel<<<(E + 255) / 256, 256, 0, stream>>>(csr, csr_src, csr_dst, eattr,
                                                       dis, norm4, norm1, n, E);

  int nodeblk = (n + 3) / 4;
  int gm512 = npad / 512, gm256 = npad / 256;
  // layer 1
  agg4x_kernel<<<nodeblk, 256, 0, stream>>>(xb, xa, rowptr, csr_src, norm4, dis, n, npad);
  sgemm_l1<<<dim3(gm512, 16), 256, 0, stream>>>(xa, W1t_hi, W1t_lo, biascat, h1, n, npad);
  // layer 2
  sgemm_l2<<<dim3(gm512, 8), 256, 0, stream>>>(h1, W2t_hi, W2t_lo, h2pre_b, n);
  agg1_kernel<4, true, 1><<<nodeblk, 256, 0, stream>>>(h2pre_b, nullptr, h2,
                                                       rowptr, csr_src, norm1,
                                                       dis + (size_t)4 * n, b2, n);
  // layer 3
  sgemm_l3<<<dim3(gm256, 4), 256, 0, stream>>>(h2, W3t_hi, W3t_lo, h3pre_b, n);
  agg1_kernel<2, false, 0><<<nodeblk, 256, 0, stream>>>(h3pre_b, h3, nullptr,
                                                        rowptr, csr_src, norm1,
                                                        dis + (size_t)4 * n, b3, n);

  pool_kernel<<<(n + 31) / 32, 128, 0, stream>>>(h3, batch, gsum, gmax, n);
  mlp_kernel<<<1, 512, 0, stream>>>(gsum, gmax, batch, n, Wm1, bm1, Wm2, bm2, out);
}

// Round 8
// 496.816 us; speedup vs baseline: 1.1336x; 1.1336x over previous
//
#include <hip/hip_runtime.h>

#define DEV_INLINE __device__ __forceinline__

typedef __attribute__((ext_vector_type(8))) short bf16x8;
typedef __attribute__((ext_vector_type(4))) float floatx4;

DEV_INLINE unsigned fencode(float f) {
  unsigned u = __float_as_uint(f);
  return (u & 0x80000000u) ? ~u : (u | 0x80000000u);
}
DEV_INLINE float fdecode(unsigned k) {
  return __uint_as_float((k & 0x80000000u) ? (k ^ 0x80000000u) : ~k);
}

DEV_INLINE unsigned short bf16_rne(float x) {
  unsigned u = __float_as_uint(x);
  unsigned r = (u + 0x7FFFu + ((u >> 16) & 1u)) >> 16;
  return (unsigned short)r;
}
DEV_INLINE float bf2f(unsigned short u) {
  return __uint_as_float(((unsigned)u) << 16);
}

#pragma clang diagnostic ignored "-Waddress-space-conversion"
DEV_INLINE void gload_lds16(const void* g, void* l) {
  __builtin_amdgcn_global_load_lds(
      (const __attribute__((address_space(1))) unsigned int*)g,
      (__attribute__((address_space(3))) unsigned int*)l, 16, 0, 0);
}

// ---------------- prep: transpose weights -> bf16 [N][K]; biases --------------
__global__ __launch_bounds__(256)
void prep_kernel(const float* __restrict__ WA, const float* __restrict__ WB,
                 const float* __restrict__ WC, const float* __restrict__ WD,
                 const float* __restrict__ bA, const float* __restrict__ bB,
                 const float* __restrict__ bC, const float* __restrict__ bD,
                 const float* __restrict__ W2, const float* __restrict__ W3,
                 unsigned short* __restrict__ W1t, unsigned short* __restrict__ W2t,
                 unsigned short* __restrict__ W3t, float* __restrict__ biascat) {
  int i = blockIdx.x * 256 + threadIdx.x;
  if (i < 65536) {  // W1 planes: [z][j out][k in]
    int z = i >> 14, rem = i & 16383, j = rem >> 7, k = rem & 127;
    const float* W = (z == 0) ? WA : (z == 1) ? WB : (z == 2) ? WC : WD;
    W1t[i] = bf16_rne(W[k * 128 + j]);
  } else if (i < 196608) {  // W2t [256][512]
    int i2 = i - 65536, j = i2 >> 9, k = i2 & 511;
    W2t[i2] = bf16_rne(W2[k * 256 + j]);
  } else if (i < 229376) {  // W3t [128][256]
    int i3 = i - 196608, j = i3 >> 8, k = i3 & 255;
    W3t[i3] = bf16_rne(W3[k * 128 + j]);
  } else if (i < 229888) {
    int i4 = i - 229376, c = i4 >> 7, j = i4 & 127;
    const float* b = (c == 0) ? bA : (c == 1) ? bB : (c == 2) ? bC : bD;
    biascat[i4] = b[j];
  }
}

// ---------------- x -> bf16 cast ----------------------------------------------
__global__ __launch_bounds__(256)
void xcast_kernel(const float* __restrict__ x, unsigned short* __restrict__ xb, int total4) {
  int i = blockIdx.x * 256 + threadIdx.x;
  if (i >= total4) return;
  float4 v = ((const float4*)x)[i];
  ushort4 o;
  o.x = bf16_rne(v.x); o.y = bf16_rne(v.y); o.z = bf16_rne(v.z); o.w = bf16_rne(v.w);
  ((ushort4*)xb)[i] = o;
}

// ---------------- in-degree histogram ----------------------------------------
__global__ __launch_bounds__(256)
void hist_kernel(const int* __restrict__ ei, int* __restrict__ cnt, int E) {
  int e = blockIdx.x * 256 + threadIdx.x;
  if (e < E) atomicAdd(&cnt[ei[E + e]], 1);
}

// ---------------- 3-level exclusive scan -------------------------------------
__global__ __launch_bounds__(256)
void scan1_kernel(const int* __restrict__ cnt, int* __restrict__ local,
                  int* __restrict__ bsum, int n) {
  __shared__ int s[256];
  int tid = threadIdx.x;
  int i = blockIdx.x * 256 + tid;
  int v = (i < n) ? cnt[i] : 0;
  s[tid] = v;
  __syncthreads();
#pragma unroll
  for (int off = 1; off < 256; off <<= 1) {
    int t = (tid >= off) ? s[tid - off] : 0;
    __syncthreads();
    s[tid] += t;
    __syncthreads();
  }
  if (i < n) local[i] = s[tid] - v;
  if (tid == 255) bsum[blockIdx.x] = s[255];
}

__global__ __launch_bounds__(256)
void scan2_kernel(int* __restrict__ bsum, int nb) {
  __shared__ int s[256];
  int tid = threadIdx.x;
  int v = (tid < nb) ? bsum[tid] : 0;
  s[tid] = v;
  __syncthreads();
#pragma unroll
  for (int off = 1; off < 256; off <<= 1) {
    int t = (tid >= off) ? s[tid - off] : 0;
    __syncthreads();
    s[tid] += t;
    __syncthreads();
  }
  if (tid < nb) bsum[tid] = s[tid] - v;  // exclusive
}

__global__ __launch_bounds__(256)
void scan3_kernel(const int* __restrict__ local, const int* __restrict__ bsum,
                  int* __restrict__ rowptr, int* __restrict__ rowwork, int n, int E) {
  int i = blockIdx.x * 256 + threadIdx.x;
  if (i < n) {
    int rp = local[i] + bsum[blockIdx.x];
    rowptr[i] = rp;
    rowwork[i] = rp;
  }
  if (i == 0) rowptr[n] = E;
}

// ---------------- CSR fill (also writes src/dst per slot) ---------------------
__global__ __launch_bounds__(256)
void fill_kernel(const int* __restrict__ ei, int* __restrict__ rowwork,
                 int* __restrict__ csr, int* __restrict__ csr_src,
                 int* __restrict__ csr_dst, int E) {
  int e = blockIdx.x * 256 + threadIdx.x;
  if (e >= E) return;
  int d = ei[E + e];
  int pos = atomicAdd(&rowwork[d], 1);
  csr[pos] = e;
  csr_src[pos] = ei[e];
  csr_dst[pos] = d;
}

// ---------------- degrees from CSR (node-centric, fused rsqrt) ----------------
__global__ __launch_bounds__(256)
void degcsr_kernel(const int* __restrict__ rowptr, const int* __restrict__ csr,
                   const float* __restrict__ eattr, float* __restrict__ dis, int n) {
  int d = blockIdx.x * 256 + threadIdx.x;
  if (d >= n) return;
  int beg = rowptr[d], end = rowptr[d + 1];
  float s0 = 1.f, s1 = 1.f, s2 = 1.f, s3 = 1.f;  // self-loop weight 1
  for (int i = beg; i < end; ++i) {
    int e = csr[i];
    float4 w = ((const float4*)eattr)[e];
    s0 += w.x; s1 += w.y; s2 += w.z; s3 += w.w;
  }
  dis[d]         = 1.0f / sqrtf(s0);
  dis[n + d]     = 1.0f / sqrtf(s1);
  dis[2 * n + d] = 1.0f / sqrtf(s2);
  dis[3 * n + d] = 1.0f / sqrtf(s3);
  dis[4 * n + d] = 1.0f / sqrtf(1.0f + (float)(end - beg));
}

// ---------------- per-CSR-slot norms -------------------------------------------
__global__ __launch_bounds__(256)
void edgeprep_kernel(const int* __restrict__ csr, const int* __restrict__ csr_src,
                     const int* __restrict__ csr_dst, const float* __restrict__ eattr,
                     const float* __restrict__ dis, float4* __restrict__ norm4,
                     float* __restrict__ norm1, int n, int E) {
  int i = blockIdx.x * 256 + threadIdx.x;
  if (i >= E) return;
  int e = csr[i], s = csr_src[i], d = csr_dst[i];
  float4 w = ((const float4*)eattr)[e];
  float4 o;
  o.x = dis[s] * w.x * dis[d];
  o.y = dis[n + s] * w.y * dis[n + d];
  o.z = dis[2 * n + s] * w.z * dis[2 * n + d];
  o.w = dis[3 * n + s] * w.w * dis[3 * n + d];
  norm4[i] = o;
  norm1[i] = dis[4 * n + s] * dis[4 * n + d];
}

// ---------------- layer-1 aggregation on bf16 x; bf16 output -------------------
__global__ __launch_bounds__(256)
void agg4x_kernel(const unsigned short* __restrict__ xb,
                  unsigned short* __restrict__ xa,
                  const int* __restrict__ rowptr, const int* __restrict__ csr_src,
                  const float4* __restrict__ norm4, const float* __restrict__ dis,
                  int n, int npad) {
  int d = blockIdx.x * 4 + (threadIdx.x >> 6);
  if (d >= n) return;
  int t = threadIdx.x & 63;
  float dc0 = dis[d], dc1 = dis[n + d], dc2 = dis[2 * n + d], dc3 = dis[3 * n + d];
  const ushort2* x2 = (const ushort2*)xb;
  ushort2 xu = x2[(size_t)d * 64 + t];
  float xvx = bf2f(xu.x), xvy = bf2f(xu.y);
  float a0x = xvx * dc0 * dc0, a0y = xvy * dc0 * dc0;
  float a1x = xvx * dc1 * dc1, a1y = xvy * dc1 * dc1;
  float a2x = xvx * dc2 * dc2, a2y = xvy * dc2 * dc2;
  float a3x = xvx * dc3 * dc3, a3y = xvy * dc3 * dc3;
  int beg = rowptr[d], end = rowptr[d + 1];
  int i = beg;
  for (; i + 4 <= end; i += 4) {
    int s0 = csr_src[i], s1 = csr_src[i + 1], s2 = csr_src[i + 2], s3 = csr_src[i + 3];
    float4 m0 = norm4[i], m1 = norm4[i + 1], m2 = norm4[i + 2], m3 = norm4[i + 3];
    ushort2 u0 = x2[(size_t)s0 * 64 + t];
    ushort2 u1 = x2[(size_t)s1 * 64 + t];
    ushort2 u2 = x2[(size_t)s2 * 64 + t];
    ushort2 u3 = x2[(size_t)s3 * 64 + t];
    float h0x = bf2f(u0.x), h0y = bf2f(u0.y);
    float h1x = bf2f(u1.x), h1y = bf2f(u1.y);
    float h2x = bf2f(u2.x), h2y = bf2f(u2.y);
    float h3x = bf2f(u3.x), h3y = bf2f(u3.y);
    a0x += h0x * m0.x; a0y += h0y * m0.x;
    a1x += h0x * m0.y; a1y += h0y * m0.y;
    a2x += h0x * m0.z; a2y += h0y * m0.z;
    a3x += h0x * m0.w; a3y += h0y * m0.w;
    a0x += h1x * m1.x; a0y += h1y * m1.x;
    a1x += h1x * m1.y; a1y += h1y * m1.y;
    a2x += h1x * m1.z; a2y += h1y * m1.z;
    a3x += h1x * m1.w; a3y += h1y * m1.w;
    a0x += h2x * m2.x; a0y += h2y * m2.x;
    a1x += h2x * m2.y; a1y += h2y * m2.y;
    a2x += h2x * m2.z; a2y += h2y * m2.z;
    a3x += h2x * m2.w; a3y += h2y * m2.w;
    a0x += h3x * m3.x; a0y += h3y * m3.x;
    a1x += h3x * m3.y; a1y += h3y * m3.y;
    a2x += h3x * m3.z; a2y += h3y * m3.z;
    a3x += h3x * m3.w; a3y += h3y * m3.w;
  }
  for (; i < end; ++i) {
    int s = csr_src[i];
    float4 m = norm4[i];
    ushort2 u = x2[(size_t)s * 64 + t];
    float hx = bf2f(u.x), hy = bf2f(u.y);
    a0x += hx * m.x; a0y += hy * m.x;
    a1x += hx * m.y; a1y += hy * m.y;
    a2x += hx * m.z; a2y += hy * m.z;
    a3x += hx * m.w; a3y += hy * m.w;
  }
  size_t plane = (size_t)npad * 128;
  size_t base = (size_t)d * 128 + 2 * t;
  float vx[4] = {a0x, a1x, a2x, a3x};
  float vy[4] = {a0y, a1y, a2y, a3y};
#pragma unroll
  for (int z = 0; z < 4; ++z) {
    ushort2 ov; ov.x = bf16_rne(vx[z]); ov.y = bf16_rne(vy[z]);
    *(ushort2*)&xa[plane * z + base] = ov;
  }
}

// ---------------- MFMA GEMM: 128x128 tile, bf16 A x bf16 B^T, dbuf LDS -------
// LDS [kquad][row] in 16B units (conflict-free, R6-verified). One barrier per
// K-iter; stage(k+1) issued after barrier, drains at next barrier (overlapped
// with the 16 MFMAs of chunk k). MODE 1: bias+relu. MODE 2: plain bf16 out.
template <int MODE>
DEV_INLINE void gemm_mfma_body(const unsigned short* __restrict__ A, int K,
                               const unsigned short* __restrict__ B,  // [N][K]+n0*K
                               int ldc, int col0, unsigned short* __restrict__ Cb,
                               const float* __restrict__ bias, int M, int row0) {
  __shared__ __align__(16) unsigned short As[2][128 * 32];
  __shared__ __align__(16) unsigned short Bs[2][128 * 32];
  int tid = threadIdx.x;
  int w = tid >> 6, lane = tid & 63;
  int quad = lane >> 4, lrow = lane & 15;
  int wm = (w >> 1) * 64, wn = (w & 1) * 64;

  floatx4 acc[4][4];
#pragma unroll
  for (int i = 0; i < 4; ++i)
#pragma unroll
    for (int j = 0; j < 4; ++j) acc[i][j] = {0.f, 0.f, 0.f, 0.f};

  auto stage = [&](int b, int k0) {
#pragma unroll
    for (int half = 0; half < 2; ++half) {
      int row = half * 64 + lane;
      int lb = (w * 128 + half * 64) * 8;
      gload_lds16(A + (size_t)(row0 + row) * K + k0 + w * 8, &As[b][lb]);
      gload_lds16(B + (size_t)row * K + k0 + w * 8, &Bs[b][lb]);
    }
  };

  int nk = K >> 5;
  stage(0, 0);
  int buf = 0;
  for (int kt = 0; kt < nk; ++kt) {
    __syncthreads();  // drains current buf's loads (and syncs readers of other buf)
    if (kt + 1 < nk) stage(buf ^ 1, (kt + 1) * 32);
    bf16x8 a_[4], b_[4];
#pragma unroll
    for (int i = 0; i < 4; ++i)
      a_[i] = *(const bf16x8*)&As[buf][(quad * 128 + wm + i * 16 + lrow) * 8];
#pragma unroll
    for (int j = 0; j < 4; ++j)
      b_[j] = *(const bf16x8*)&Bs[buf][(quad * 128 + wn + j * 16 + lrow) * 8];
#pragma unroll
    for (int j = 0; j < 4; ++j)
#pragma unroll
      for (int i = 0; i < 4; ++i)
        acc[i][j] = __builtin_amdgcn_mfma_f32_16x16x32_bf16(a_[i], b_[j], acc[i][j], 0, 0, 0);
    buf ^= 1;
  }
  // epilogue: C/D layout col=lane&15, row=quad*4+reg
#pragma unroll
  for (int i = 0; i < 4; ++i) {
#pragma unroll
    for (int j = 0; j < 4; ++j) {
      int colL = wn + j * 16 + lrow;
#pragma unroll
      for (int r = 0; r < 4; ++r) {
        int row = row0 + wm + i * 16 + quad * 4 + r;
        if (row < M) {
          float v = acc[i][j][r];
          if (MODE == 1) v = fmaxf(v + bias[colL], 0.0f);
          Cb[(size_t)row * ldc + col0 + colL] = bf16_rne(v);
        }
      }
    }
  }
}

__global__ __launch_bounds__(256)
void gemm_l1_mfma(const unsigned short* __restrict__ xa,
                  const unsigned short* __restrict__ W1t,
                  const float* __restrict__ biascat,
                  unsigned short* __restrict__ h1, int M, int npad) {
  int z = blockIdx.z;
  gemm_mfma_body<1>(xa + (size_t)z * npad * 128, 128, W1t + z * 16384,
                    512, z * 128, h1, biascat + z * 128, M, blockIdx.x * 128);
}

__global__ __launch_bounds__(256)
void gemm_bf16out(const unsigned short* __restrict__ A, int K,
                  const unsigned short* __restrict__ B,
                  unsigned short* __restrict__ Cb, int ldc, int M) {
  gemm_mfma_body<2>(A, K, B + (size_t)blockIdx.y * 128 * K, ldc,
                    blockIdx.y * 128, Cb, nullptr, M, blockIdx.x * 128);
}

// ---------------- layers 2/3 aggregation: bf16 gather, 4-edge unroll ----------
template <int VEC, bool RELU, int OMODE>
__global__ __launch_bounds__(256)
void agg1_kernel(const unsigned short* __restrict__ hb, float* __restrict__ out,
                 unsigned short* __restrict__ ob,
                 const int* __restrict__ rowptr, const int* __restrict__ csr_src,
                 const float* __restrict__ norm1, const float* __restrict__ dis1,
                 const float* __restrict__ bias, int n) {
  constexpr int DOUT = VEC * 64;
  int d = blockIdx.x * 4 + (threadIdx.x >> 6);
  if (d >= n) return;
  int t = threadIdx.x & 63;
  float dd = dis1[d];
  float acc[VEC];
  {
    float sw = dd * dd;
#pragma unroll
    for (int k = 0; k < VEC; ++k) acc[k] = bf2f(hb[(size_t)d * DOUT + t * VEC + k]) * sw;
  }
  int beg = rowptr[d], end = rowptr[d + 1];
  int i = beg;
  for (; i + 4 <= end; i += 4) {
    int s0 = csr_src[i], s1 = csr_src[i + 1], s2 = csr_src[i + 2], s3 = csr_src[i + 3];
    float m0 = norm1[i], m1 = norm1[i + 1], m2 = norm1[i + 2], m3 = norm1[i + 3];
    if (VEC == 4) {
      ushort4 u0 = *(const ushort4*)&hb[(size_t)s0 * DOUT + t * 4];
      ushort4 u1 = *(const ushort4*)&hb[(size_t)s1 * DOUT + t * 4];
      ushort4 u2 = *(const ushort4*)&hb[(size_t)s2 * DOUT + t * 4];
      ushort4 u3 = *(const ushort4*)&hb[(size_t)s3 * DOUT + t * 4];
      acc[0] += bf2f(u0.x) * m0; acc[1] += bf2f(u0.y) * m0;
      acc[2 % VEC] += bf2f(u0.z) * m0; acc[3 % VEC] += bf2f(u0.w) * m0;
      acc[0] += bf2f(u1.x) * m1; acc[1] += bf2f(u1.y) * m1;
      acc[2 % VEC] += bf2f(u1.z) * m1; acc[3 % VEC] += bf2f(u1.w) * m1;
      acc[0] += bf2f(u2.x) * m2; acc[1] += bf2f(u2.y) * m2;
      acc[2 % VEC] += bf2f(u2.z) * m2; acc[3 % VEC] += bf2f(u2.w) * m2;
      acc[0] += bf2f(u3.x) * m3; acc[1] += bf2f(u3.y) * m3;
      acc[2 % VEC] += bf2f(u3.z) * m3; acc[3 % VEC] += bf2f(u3.w) * m3;
    } else {
      ushort2 u0 = *(const ushort2*)&hb[(size_t)s0 * DOUT + t * 2];
      ushort2 u1 = *(const ushort2*)&hb[(size_t)s1 * DOUT + t * 2];
      ushort2 u2 = *(const ushort2*)&hb[(size_t)s2 * DOUT + t * 2];
      ushort2 u3 = *(const ushort2*)&hb[(size_t)s3 * DOUT + t * 2];
      acc[0] += bf2f(u0.x) * m0; acc[1 % VEC] += bf2f(u0.y) * m0;
      acc[0] += bf2f(u1.x) * m1; acc[1 % VEC] += bf2f(u1.y) * m1;
      acc[0] += bf2f(u2.x) * m2; acc[1 % VEC] += bf2f(u2.y) * m2;
      acc[0] += bf2f(u3.x) * m3; acc[1 % VEC] += bf2f(u3.y) * m3;
    }
  }
  for (; i < end; ++i) {
    int s = csr_src[i];
    float nrm = norm1[i];
    if (VEC == 4) {
      ushort4 u = *(const ushort4*)&hb[(size_t)s * DOUT + t * 4];
      acc[0] += bf2f(u.x) * nrm; acc[1] += bf2f(u.y) * nrm;
      acc[2 % VEC] += bf2f(u.z) * nrm; acc[3 % VEC] += bf2f(u.w) * nrm;
    } else {
      ushort2 u = *(const ushort2*)&hb[(size_t)s * DOUT + t * 2];
      acc[0] += bf2f(u.x) * nrm; acc[1 % VEC] += bf2f(u.y) * nrm;
    }
  }
#pragma unroll
  for (int k = 0; k < VEC; ++k) {
    float r = acc[k] + bias[t * VEC + k];
    if (RELU) r = fmaxf(r, 0.0f);
    if (OMODE == 1) {
      ob[(size_t)d * DOUT + t * VEC + k] = bf16_rne(r);
    } else {
      out[(size_t)d * DOUT + t * VEC + k] = r;
    }
  }
}

// ---------------- pooling: per-graph sum + max (encoded uint) -----------------
__global__ __launch_bounds__(128)
void pool_kernel(const float* __restrict__ h3, const int* __restrict__ batch,
                 float* __restrict__ gsum, unsigned* __restrict__ gmax, int n) {
  int c = threadIdx.x;
  int start = blockIdx.x * 32;
  int end = min(start + 32, n);
  int curg = -1;
  float s = 0.0f, m = -3.402823466e38f;
  for (int i = start; i < end; ++i) {
    int g = batch[i];
    if (g != curg) {
      if (curg >= 0) {
        atomicAdd(&gsum[curg * 128 + c], s);
        atomicMax(&gmax[curg * 128 + c], fencode(m));
      }
      curg = g; s = 0.0f; m = -3.402823466e38f;
    }
    float v = h3[(size_t)i * 128 + c];
    s += v;
    m = fmaxf(m, v);
  }
  if (curg >= 0) {
    atomicAdd(&gsum[curg * 128 + c], s);
    atomicMax(&gmax[curg * 128 + c], fencode(m));
  }
}

// ---------------- final MLP; per-graph counts via binary search ---------------
__global__ __launch_bounds__(512)
void mlp_kernel(const float* __restrict__ gsum, const unsigned* __restrict__ gmax,
                const int* __restrict__ batch, int n, const float* __restrict__ Wm1,
                const float* __restrict__ bm1, const float* __restrict__ Wm2,
                const float* __restrict__ bm2, float* __restrict__ out) {
  __shared__ float hid[64][8];
  int t = threadIdx.x;
  int gi = t >> 3, u = t & 7;
  auto lb = [&](int key) {
    int lo = 0, hi = n;
    while (lo < hi) {
      int mid = (lo + hi) >> 1;
      if (batch[mid] < key) lo = mid + 1; else hi = mid;
    }
    return lo;
  };
  int cnt = lb(gi + 1) - lb(gi);
  float inv = 1.0f / fmaxf((float)cnt, 1.0f);
  float s = bm1[u];
  for (int k = 0; k < 128; ++k) {
    float mean = gsum[gi * 128 + k] * inv;
    s += mean * Wm1[k * 8 + u];
  }
  for (int k = 0; k < 128; ++k) {
    float mx = (cnt > 0) ? fdecode(gmax[gi * 128 + k]) : 0.0f;
    s += mx * Wm1[(128 + k) * 8 + u];
  }
  hid[gi][u] = fmaxf(s, 0.0f);
  __syncthreads();
  if (t < 128) {
    int g2 = t >> 1, o = t & 1;
    float s2 = bm2[o];
#pragma unroll
    for (int uu = 0; uu < 8; ++uu) s2 += hid[g2][uu] * Wm2[uu * 2 + o];
    out[g2 * 2 + o] = s2;
  }
}

extern "C" void kernel_launch(void* const* d_in, const int* in_sizes, int n_in,
                              void* d_out, int out_size, void* d_ws, size_t ws_size,
                              hipStream_t stream) {
  const float* x     = (const float*)d_in[0];
  const int*   ei    = (const int*)d_in[1];
  const float* eattr = (const float*)d_in[2];
  const int*   batch = (const int*)d_in[3];
  const float* W1A = (const float*)d_in[4],  *b1A = (const float*)d_in[5];
  const float* W1B = (const float*)d_in[6],  *b1B = (const float*)d_in[7];
  const float* W1C = (const float*)d_in[8],  *b1C = (const float*)d_in[9];
  const float* W1D = (const float*)d_in[10], *b1D = (const float*)d_in[11];
  const float* W2  = (const float*)d_in[12], *b2  = (const float*)d_in[13];
  const float* W3  = (const float*)d_in[14], *b3  = (const float*)d_in[15];
  const float* Wm1 = (const float*)d_in[16], *bm1 = (const float*)d_in[17];
  const float* Wm2 = (const float*)d_in[18], *bm2 = (const float*)d_in[19];
  float* out = (float*)d_out;

  const int n = in_sizes[0] / 128;
  const int E = in_sizes[1] / 2;
  const int npad = (n + 127) & ~127;
  const int nmb = npad / 128;

  char* ws = (char*)d_ws;
  size_t off = 0;
  auto alloc = [&](size_t bytes) -> void* {
    void* p = ws + off;
    off += (bytes + 255) & ~(size_t)255;
    return p;
  };

  float*    dis     = (float*)alloc((size_t)5 * n * 4);
  int*      rowptr  = (int*)alloc(((size_t)n + 1) * 4);
  int*      rowwork = (int*)alloc((size_t)n * 4);
  int*      local   = (int*)alloc((size_t)n * 4);
  int*      bsum    = (int*)alloc(256 * 4);
  // ---- zero block start ----
  size_t zoff = off;
  int*      cnt     = (int*)alloc((size_t)n * 4);
  float*    gsum    = (float*)alloc(64 * 128 * 4);
  unsigned* gmax    = (unsigned*)alloc(64 * 128 * 4);
  size_t zbytes = off - zoff;
  // ---- zero block end ----
  int*      csr     = (int*)alloc((size_t)E * 4);
  int*      csr_src = (int*)alloc((size_t)E * 4);
  int*      csr_dst = (int*)alloc((size_t)E * 4);
  float4*   norm4   = (float4*)alloc((size_t)E * 16);
  float*    norm1   = (float*)alloc((size_t)E * 4);
  unsigned short* W1t = (unsigned short*)alloc(65536 * 2);
  unsigned short* W2t = (unsigned short*)alloc(131072 * 2);
  unsigned short* W3t = (unsigned short*)alloc(32768 * 2);
  float*    biascat = (float*)alloc(512 * 4);
  unsigned short* xb   = (unsigned short*)alloc((size_t)npad * 128 * 2);
  unsigned short* bufA = (unsigned short*)alloc((size_t)npad * 512 * 2);  // xa / h2pre / h3pre
  unsigned short* bufB = (unsigned short*)alloc((size_t)npad * 512 * 2);  // h1 / h2+h3
  alloc(4096);  // guard pad

  unsigned short* xa      = bufA;                     // 4 planes [npad,128] bf16
  unsigned short* h1      = bufB;                     // [npad,512] bf16
  unsigned short* h2pre_b = bufA;                     // [npad,256] bf16 (xa dead)
  unsigned short* h2      = bufB;                     // [npad,256] bf16 (h1 dead after gemm_l2)
  unsigned short* h3pre_b = bufA;                     // [npad,128] bf16 (h2pre dead)
  float*          h3      = (float*)(bufB + (size_t)npad * 256);  // [npad,128] fp32

  hipMemsetAsync(ws + zoff, 0, zbytes, stream);

  prep_kernel<<<(229888 + 255) / 256, 256, 0, stream>>>(
      W1A, W1B, W1C, W1D, b1A, b1B, b1C, b1D, W2, W3,
      W1t, W2t, W3t, biascat);
  xcast_kernel<<<((n * 32) + 255) / 256, 256, 0, stream>>>(x, xb, n * 32);

  int nb = (n + 255) / 256;
  hist_kernel<<<(E + 255) / 256, 256, 0, stream>>>(ei, cnt, E);
  scan1_kernel<<<nb, 256, 0, stream>>>(cnt, local, bsum, n);
  scan2_kernel<<<1, 256, 0, stream>>>(bsum, nb);
  scan3_kernel<<<nb, 256, 0, stream>>>(local, bsum, rowptr, rowwork, n, E);
  fill_kernel<<<(E + 255) / 256, 256, 0, stream>>>(ei, rowwork, csr, csr_src, csr_dst, E);
  degcsr_kernel<<<(n + 255) / 256, 256, 0, stream>>>(rowptr, csr, eattr, dis, n);
  edgeprep_kernel<<<(E + 255) / 256, 256, 0, stream>>>(csr, csr_src, csr_dst, eattr,
                                                       dis, norm4, norm1, n, E);

  int nodeblk = (n + 3) / 4;
  // layer 1
  agg4x_kernel<<<nodeblk, 256, 0, stream>>>(xb, xa, rowptr, csr_src, norm4, dis, n, npad);
  gemm_l1_mfma<<<dim3(nmb, 1, 4), 256, 0, stream>>>(xa, W1t, biascat, h1, n, npad);
  // layer 2
  gemm_bf16out<<<dim3(nmb, 2), 256, 0, stream>>>(h1, 512, W2t, h2pre_b, 256, n);
  agg1_kernel<4, true, 1><<<nodeblk, 256, 0, stream>>>(h2pre_b, nullptr, h2,
                                                       rowptr, csr_src, norm1,
                                                       dis + (size_t)4 * n, b2, n);
  // layer 3
  gemm_bf16out<<<dim3(nmb, 1), 256, 0, stream>>>(h2, 256, W3t, h3pre_b, 128, n);
  agg1_kernel<2, false, 0><<<nodeblk, 256, 0, stream>>>(h3pre_b, h3, nullptr,
                                                        rowptr, csr_src, norm1,
                                                        dis + (size_t)4 * n, b3, n);

  pool_kernel<<<(n + 31) / 32, 128, 0, stream>>>(h3, batch, gsum, gmax, n);
  mlp_kernel<<<1, 512, 0, stream>>>(gsum, gmax, batch, n, Wm1, bm1, Wm2, bm2, out);
}

// Round 9
// 477.252 us; speedup vs baseline: 1.1800x; 1.0410x over previous
//
#include <hip/hip_runtime.h>

#define DEV_INLINE __device__ __forceinline__

typedef __attribute__((ext_vector_type(8))) short bf16x8;
typedef __attribute__((ext_vector_type(4))) float floatx4;

DEV_INLINE unsigned fencode(float f) {
  unsigned u = __float_as_uint(f);
  return (u & 0x80000000u) ? ~u : (u | 0x80000000u);
}
DEV_INLINE float fdecode(unsigned k) {
  return __uint_as_float((k & 0x80000000u) ? (k ^ 0x80000000u) : ~k);
}

DEV_INLINE unsigned short bf16_rne(float x) {
  unsigned u = __float_as_uint(x);
  unsigned r = (u + 0x7FFFu + ((u >> 16) & 1u)) >> 16;
  return (unsigned short)r;
}
DEV_INLINE float bf2f(unsigned short u) {
  return __uint_as_float(((unsigned)u) << 16);
}

#pragma clang diagnostic ignored "-Waddress-space-conversion"
DEV_INLINE void gload_lds16(const void* g, void* l) {
  __builtin_amdgcn_global_load_lds(
      (const __attribute__((address_space(1))) unsigned int*)g,
      (__attribute__((address_space(3))) unsigned int*)l, 16, 0, 0);
}

// ---------------- prep: weights -> bf16 [N][K]; biases; x -> bf16 --------------
__global__ __launch_bounds__(256)
void prep_kernel(const float* __restrict__ WA, const float* __restrict__ WB,
                 const float* __restrict__ WC, const float* __restrict__ WD,
                 const float* __restrict__ bA, const float* __restrict__ bB,
                 const float* __restrict__ bC, const float* __restrict__ bD,
                 const float* __restrict__ W2, const float* __restrict__ W3,
                 unsigned short* __restrict__ W1t, unsigned short* __restrict__ W2t,
                 unsigned short* __restrict__ W3t, float* __restrict__ biascat,
                 const float* __restrict__ x, unsigned short* __restrict__ xb,
                 int total4) {
  int i = blockIdx.x * 256 + threadIdx.x;
  if (i < 65536) {  // W1 planes: [z][j out][k in]
    int z = i >> 14, rem = i & 16383, j = rem >> 7, k = rem & 127;
    const float* W = (z == 0) ? WA : (z == 1) ? WB : (z == 2) ? WC : WD;
    W1t[i] = bf16_rne(W[k * 128 + j]);
  } else if (i < 196608) {  // W2t [256][512]
    int i2 = i - 65536, j = i2 >> 9, k = i2 & 511;
    W2t[i2] = bf16_rne(W2[k * 256 + j]);
  } else if (i < 229376) {  // W3t [128][256]
    int i3 = i - 196608, j = i3 >> 8, k = i3 & 255;
    W3t[i3] = bf16_rne(W3[k * 128 + j]);
  } else if (i < 229888) {
    int i4 = i - 229376, c = i4 >> 7, j = i4 & 127;
    const float* b = (c == 0) ? bA : (c == 1) ? bB : (c == 2) ? bC : bD;
    biascat[i4] = b[j];
  }
  if (i < total4) {  // x cast (float4 granules)
    float4 v = ((const float4*)x)[i];
    ushort4 o;
    o.x = bf16_rne(v.x); o.y = bf16_rne(v.y); o.z = bf16_rne(v.z); o.w = bf16_rne(v.w);
    ((ushort4*)xb)[i] = o;
  }
}

// ---------------- in-degree histogram ----------------------------------------
__global__ __launch_bounds__(256)
void hist_kernel(const int* __restrict__ ei, int* __restrict__ cnt, int E) {
  int e = blockIdx.x * 256 + threadIdx.x;
  if (e < E) atomicAdd(&cnt[ei[E + e]], 1);
}

// ---------------- 3-level exclusive scan -------------------------------------
__global__ __launch_bounds__(256)
void scan1_kernel(const int* __restrict__ cnt, int* __restrict__ local,
                  int* __restrict__ bsum, int n) {
  __shared__ int s[256];
  int tid = threadIdx.x;
  int i = blockIdx.x * 256 + tid;
  int v = (i < n) ? cnt[i] : 0;
  s[tid] = v;
  __syncthreads();
#pragma unroll
  for (int off = 1; off < 256; off <<= 1) {
    int t = (tid >= off) ? s[tid - off] : 0;
    __syncthreads();
    s[tid] += t;
    __syncthreads();
  }
  if (i < n) local[i] = s[tid] - v;
  if (tid == 255) bsum[blockIdx.x] = s[255];
}

__global__ __launch_bounds__(256)
void scan2_kernel(int* __restrict__ bsum, int nb) {
  __shared__ int s[256];
  int tid = threadIdx.x;
  int v = (tid < nb) ? bsum[tid] : 0;
  s[tid] = v;
  __syncthreads();
#pragma unroll
  for (int off = 1; off < 256; off <<= 1) {
    int t = (tid >= off) ? s[tid - off] : 0;
    __syncthreads();
    s[tid] += t;
    __syncthreads();
  }
  if (tid < nb) bsum[tid] = s[tid] - v;  // exclusive
}

__global__ __launch_bounds__(256)
void scan3_kernel(const int* __restrict__ local, const int* __restrict__ bsum,
                  int* __restrict__ rowptr, int* __restrict__ rowwork, int n, int E) {
  int i = blockIdx.x * 256 + threadIdx.x;
  if (i < n) {
    int rp = local[i] + bsum[blockIdx.x];
    rowptr[i] = rp;
    rowwork[i] = rp;
  }
  if (i == 0) rowptr[n] = E;
}

// ---------------- CSR fill: slot gets src, dst, AND edge weights --------------
__global__ __launch_bounds__(256)
void fill_kernel(const int* __restrict__ ei, const float* __restrict__ eattr,
                 int* __restrict__ rowwork, int* __restrict__ csr_src,
                 int* __restrict__ csr_dst, float4* __restrict__ csr_w, int E) {
  int e = blockIdx.x * 256 + threadIdx.x;
  if (e >= E) return;
  int d = ei[E + e];
  int pos = atomicAdd(&rowwork[d], 1);
  csr_src[pos] = ei[e];
  csr_dst[pos] = d;
  csr_w[pos] = ((const float4*)eattr)[e];
}

// ---------------- degrees: contiguous csr_w stream (no indirection) -----------
__global__ __launch_bounds__(256)
void degcsr_kernel(const int* __restrict__ rowptr, const float4* __restrict__ csr_w,
                   float* __restrict__ dis, int n) {
  int d = blockIdx.x * 256 + threadIdx.x;
  if (d >= n) return;
  int beg = rowptr[d], end = rowptr[d + 1];
  float s0 = 1.f, s1 = 1.f, s2 = 1.f, s3 = 1.f;  // self-loop weight 1
  for (int i = beg; i < end; ++i) {
    float4 w = csr_w[i];
    s0 += w.x; s1 += w.y; s2 += w.z; s3 += w.w;
  }
  dis[d]         = 1.0f / sqrtf(s0);
  dis[n + d]     = 1.0f / sqrtf(s1);
  dis[2 * n + d] = 1.0f / sqrtf(s2);
  dis[3 * n + d] = 1.0f / sqrtf(s3);
  dis[4 * n + d] = 1.0f / sqrtf(1.0f + (float)(end - beg));
}

// ---------------- per-CSR-slot norms (streaming csr_w) -------------------------
__global__ __launch_bounds__(256)
void edgeprep_kernel(const int* __restrict__ csr_src, const int* __restrict__ csr_dst,
                     const float4* __restrict__ csr_w, const float* __restrict__ dis,
                     float4* __restrict__ norm4, float* __restrict__ norm1,
                     int n, int E) {
  int i = blockIdx.x * 256 + threadIdx.x;
  if (i >= E) return;
  int s = csr_src[i], d = csr_dst[i];
  float4 w = csr_w[i];
  float4 o;
  o.x = dis[s] * w.x * dis[d];
  o.y = dis[n + s] * w.y * dis[n + d];
  o.z = dis[2 * n + s] * w.z * dis[2 * n + d];
  o.w = dis[3 * n + s] * w.w * dis[3 * n + d];
  norm4[i] = o;
  norm1[i] = dis[4 * n + s] * dis[4 * n + d];
}

// ---------------- layer-1 aggregation on bf16 x; bf16 output -------------------
__global__ __launch_bounds__(256)
void agg4x_kernel(const unsigned short* __restrict__ xb,
                  unsigned short* __restrict__ xa,
                  const int* __restrict__ rowptr, const int* __restrict__ csr_src,
                  const float4* __restrict__ norm4, const float* __restrict__ dis,
                  int n, int npad) {
  int d = blockIdx.x * 4 + (threadIdx.x >> 6);
  if (d >= n) return;
  int t = threadIdx.x & 63;
  float dc0 = dis[d], dc1 = dis[n + d], dc2 = dis[2 * n + d], dc3 = dis[3 * n + d];
  const ushort2* x2 = (const ushort2*)xb;
  ushort2 xu = x2[(size_t)d * 64 + t];
  float xvx = bf2f(xu.x), xvy = bf2f(xu.y);
  float a0x = xvx * dc0 * dc0, a0y = xvy * dc0 * dc0;
  float a1x = xvx * dc1 * dc1, a1y = xvy * dc1 * dc1;
  float a2x = xvx * dc2 * dc2, a2y = xvy * dc2 * dc2;
  float a3x = xvx * dc3 * dc3, a3y = xvy * dc3 * dc3;
  int beg = rowptr[d], end = rowptr[d + 1];
  int i = beg;
  for (; i + 4 <= end; i += 4) {
    int s0 = csr_src[i], s1 = csr_src[i + 1], s2 = csr_src[i + 2], s3 = csr_src[i + 3];
    float4 m0 = norm4[i], m1 = norm4[i + 1], m2 = norm4[i + 2], m3 = norm4[i + 3];
    ushort2 u0 = x2[(size_t)s0 * 64 + t];
    ushort2 u1 = x2[(size_t)s1 * 64 + t];
    ushort2 u2 = x2[(size_t)s2 * 64 + t];
    ushort2 u3 = x2[(size_t)s3 * 64 + t];
    float h0x = bf2f(u0.x), h0y = bf2f(u0.y);
    float h1x = bf2f(u1.x), h1y = bf2f(u1.y);
    float h2x = bf2f(u2.x), h2y = bf2f(u2.y);
    float h3x = bf2f(u3.x), h3y = bf2f(u3.y);
    a0x += h0x * m0.x; a0y += h0y * m0.x;
    a1x += h0x * m0.y; a1y += h0y * m0.y;
    a2x += h0x * m0.z; a2y += h0y * m0.z;
    a3x += h0x * m0.w; a3y += h0y * m0.w;
    a0x += h1x * m1.x; a0y += h1y * m1.x;
    a1x += h1x * m1.y; a1y += h1y * m1.y;
    a2x += h1x * m1.z; a2y += h1y * m1.z;
    a3x += h1x * m1.w; a3y += h1y * m1.w;
    a0x += h2x * m2.x; a0y += h2y * m2.x;
    a1x += h2x * m2.y; a1y += h2y * m2.y;
    a2x += h2x * m2.z; a2y += h2y * m2.z;
    a3x += h2x * m2.w; a3y += h2y * m2.w;
    a0x += h3x * m3.x; a0y += h3y * m3.x;
    a1x += h3x * m3.y; a1y += h3y * m3.y;
    a2x += h3x * m3.z; a2y += h3y * m3.z;
    a3x += h3x * m3.w; a3y += h3y * m3.w;
  }
  for (; i < end; ++i) {
    int s = csr_src[i];
    float4 m = norm4[i];
    ushort2 u = x2[(size_t)s * 64 + t];
    float hx = bf2f(u.x), hy = bf2f(u.y);
    a0x += hx * m.x; a0y += hy * m.x;
    a1x += hx * m.y; a1y += hy * m.y;
    a2x += hx * m.z; a2y += hy * m.z;
    a3x += hx * m.w; a3y += hy * m.w;
  }
  size_t plane = (size_t)npad * 128;
  size_t base = (size_t)d * 128 + 2 * t;
  float vx[4] = {a0x, a1x, a2x, a3x};
  float vy[4] = {a0y, a1y, a2y, a3y};
#pragma unroll
  for (int z = 0; z < 4; ++z) {
    ushort2 ov; ov.x = bf16_rne(vx[z]); ov.y = bf16_rne(vy[z]);
    *(ushort2*)&xa[plane * z + base] = ov;
  }
}

// ---------------- MFMA GEMM (4-wave, 128x128 tile, dbuf) — l1 & l3 ------------
template <int MODE>
DEV_INLINE void gemm_mfma_body(const unsigned short* __restrict__ A, int K,
                               const unsigned short* __restrict__ B,
                               int ldc, int col0, unsigned short* __restrict__ Cb,
                               const float* __restrict__ bias, int M, int row0) {
  __shared__ __align__(16) unsigned short As[2][128 * 32];
  __shared__ __align__(16) unsigned short Bs[2][128 * 32];
  int tid = threadIdx.x;
  int w = tid >> 6, lane = tid & 63;
  int quad = lane >> 4, lrow = lane & 15;
  int wm = (w >> 1) * 64, wn = (w & 1) * 64;

  floatx4 acc[4][4];
#pragma unroll
  for (int i = 0; i < 4; ++i)
#pragma unroll
    for (int j = 0; j < 4; ++j) acc[i][j] = {0.f, 0.f, 0.f, 0.f};

  auto stage = [&](int b, int k0) {
#pragma unroll
    for (int half = 0; half < 2; ++half) {
      int row = half * 64 + lane;
      int lb = (w * 128 + half * 64) * 8;
      gload_lds16(A + (size_t)(row0 + row) * K + k0 + w * 8, &As[b][lb]);
      gload_lds16(B + (size_t)row * K + k0 + w * 8, &Bs[b][lb]);
    }
  };

  int nk = K >> 5;
  stage(0, 0);
  int buf = 0;
  for (int kt = 0; kt < nk; ++kt) {
    __syncthreads();
    if (kt + 1 < nk) stage(buf ^ 1, (kt + 1) * 32);
    bf16x8 a_[4], b_[4];
#pragma unroll
    for (int i = 0; i < 4; ++i)
      a_[i] = *(const bf16x8*)&As[buf][(quad * 128 + wm + i * 16 + lrow) * 8];
#pragma unroll
    for (int j = 0; j < 4; ++j)
      b_[j] = *(const bf16x8*)&Bs[buf][(quad * 128 + wn + j * 16 + lrow) * 8];
#pragma unroll
    for (int j = 0; j < 4; ++j)
#pragma unroll
      for (int i = 0; i < 4; ++i)
        acc[i][j] = __builtin_amdgcn_mfma_f32_16x16x32_bf16(a_[i], b_[j], acc[i][j], 0, 0, 0);
    buf ^= 1;
  }
#pragma unroll
  for (int i = 0; i < 4; ++i) {
#pragma unroll
    for (int j = 0; j < 4; ++j) {
      int colL = wn + j * 16 + lrow;
#pragma unroll
      for (int r = 0; r < 4; ++r) {
        int row = row0 + wm + i * 16 + quad * 4 + r;
        if (row < M) {
          float v = acc[i][j][r];
          if (MODE == 1) v = fmaxf(v + bias[colL], 0.0f);
          Cb[(size_t)row * ldc + col0 + colL] = bf16_rne(v);
        }
      }
    }
  }
}

__global__ __launch_bounds__(256)
void gemm_l1_mfma(const unsigned short* __restrict__ xa,
                  const unsigned short* __restrict__ W1t,
                  const float* __restrict__ biascat,
                  unsigned short* __restrict__ h1, int M, int npad) {
  int z = blockIdx.z;
  gemm_mfma_body<1>(xa + (size_t)z * npad * 128, 128, W1t + z * 16384,
                    512, z * 128, h1, biascat + z * 128, M, blockIdx.x * 128);
}

__global__ __launch_bounds__(256)
void gemm_bf16out(const unsigned short* __restrict__ A, int K,
                  const unsigned short* __restrict__ B,
                  unsigned short* __restrict__ Cb, int ldc, int M) {
  gemm_mfma_body<2>(A, K, B + (size_t)blockIdx.y * 128 * K, ldc,
                    blockIdx.y * 128, Cb, nullptr, M, blockIdx.x * 128);
}

// ---------------- wide l2 GEMM: 512 thr = 8 waves, 128x256 tile, dbuf ---------
// A (h1 [npad,512]) staged ONCE per k-chunk for all 256 cols. Wave w covers
// 64x64 quadrant: wm=(w>>2)*64, wn=(w&3)*64. LDS [kquad][row] 16B units.
__global__ __launch_bounds__(512)
void gemm_l2_wide(const unsigned short* __restrict__ A,
                  const unsigned short* __restrict__ B,  // W2t [256][512]
                  unsigned short* __restrict__ Cb, int M) {
  constexpr int K = 512;
  __shared__ __align__(16) unsigned short As[2][128 * 32];
  __shared__ __align__(16) unsigned short Bs[2][256 * 32];
  int tid = threadIdx.x;
  int w = tid >> 6, lane = tid & 63;
  int quad = lane >> 4, lrow = lane & 15;
  int wm = (w >> 2) * 64, wn = (w & 3) * 64;
  int row0 = blockIdx.x * 128;
  int u0 = w * 64;  // wave-uniform LDS unit base

  floatx4 acc[4][4];
#pragma unroll
  for (int i = 0; i < 4; ++i)
#pragma unroll
    for (int j = 0; j < 4; ++j) acc[i][j] = {0.f, 0.f, 0.f, 0.f};

  auto stage = [&](int b, int k0) {
    // A: 512 units (row = u&127, kquad = u>>7), u = tid
    gload_lds16(A + (size_t)(row0 + (tid & 127)) * K + k0 + (tid >> 7) * 8,
                &As[b][u0 * 8]);
    // B: 1024 units (row = u&255, kquad = u>>8), u = inst*512 + tid
#pragma unroll
    for (int inst = 0; inst < 2; ++inst) {
      int u = inst * 512 + tid;
      gload_lds16(B + (size_t)(u & 255) * K + k0 + (u >> 8) * 8,
                  &Bs[b][(inst * 512 + u0) * 8]);
    }
  };

  stage(0, 0);
  int buf = 0;
#pragma unroll 1
  for (int kt = 0; kt < 16; ++kt) {
    __syncthreads();
    if (kt + 1 < 16) stage(buf ^ 1, (kt + 1) * 32);
    bf16x8 a_[4], b_[4];
#pragma unroll
    for (int i = 0; i < 4; ++i)
      a_[i] = *(const bf16x8*)&As[buf][(quad * 128 + wm + i * 16 + lrow) * 8];
#pragma unroll
    for (int j = 0; j < 4; ++j)
      b_[j] = *(const bf16x8*)&Bs[buf][(quad * 256 + wn + j * 16 + lrow) * 8];
#pragma unroll
    for (int j = 0; j < 4; ++j)
#pragma unroll
      for (int i = 0; i < 4; ++i)
        acc[i][j] = __builtin_amdgcn_mfma_f32_16x16x32_bf16(a_[i], b_[j], acc[i][j], 0, 0, 0);
    buf ^= 1;
  }
#pragma unroll
  for (int i = 0; i < 4; ++i) {
#pragma unroll
    for (int j = 0; j < 4; ++j) {
      int colL = wn + j * 16 + lrow;
#pragma unroll
      for (int r = 0; r < 4; ++r) {
        int row = row0 + wm + i * 16 + quad * 4 + r;
        if (row < M) Cb[(size_t)row * 256 + colL] = bf16_rne(acc[i][j][r]);
      }
    }
  }
}

// ---------------- layers 2/3 aggregation: bf16 gather, 4-edge unroll ----------
template <int VEC, bool RELU, int OMODE>
__global__ __launch_bounds__(256)
void agg1_kernel(const unsigned short* __restrict__ hb, float* __restrict__ out,
                 unsigned short* __restrict__ ob,
                 const int* __restrict__ rowptr, const int* __restrict__ csr_src,
                 const float* __restrict__ norm1, const float* __restrict__ dis1,
                 const float* __restrict__ bias, int n) {
  constexpr int DOUT = VEC * 64;
  int d = blockIdx.x * 4 + (threadIdx.x >> 6);
  if (d >= n) return;
  int t = threadIdx.x & 63;
  float dd = dis1[d];
  float acc[VEC];
  {
    float sw = dd * dd;
#pragma unroll
    for (int k = 0; k < VEC; ++k) acc[k] = bf2f(hb[(size_t)d * DOUT + t * VEC + k]) * sw;
  }
  int beg = rowptr[d], end = rowptr[d + 1];
  int i = beg;
  for (; i + 4 <= end; i += 4) {
    int s0 = csr_src[i], s1 = csr_src[i + 1], s2 = csr_src[i + 2], s3 = csr_src[i + 3];
    float m0 = norm1[i], m1 = norm1[i + 1], m2 = norm1[i + 2], m3 = norm1[i + 3];
    if (VEC == 4) {
      ushort4 u0 = *(const ushort4*)&hb[(size_t)s0 * DOUT + t * 4];
      ushort4 u1 = *(const ushort4*)&hb[(size_t)s1 * DOUT + t * 4];
      ushort4 u2 = *(const ushort4*)&hb[(size_t)s2 * DOUT + t * 4];
      ushort4 u3 = *(const ushort4*)&hb[(size_t)s3 * DOUT + t * 4];
      acc[0] += bf2f(u0.x) * m0; acc[1] += bf2f(u0.y) * m0;
      acc[2 % VEC] += bf2f(u0.z) * m0; acc[3 % VEC] += bf2f(u0.w) * m0;
      acc[0] += bf2f(u1.x) * m1; acc[1] += bf2f(u1.y) * m1;
      acc[2 % VEC] += bf2f(u1.z) * m1; acc[3 % VEC] += bf2f(u1.w) * m1;
      acc[0] += bf2f(u2.x) * m2; acc[1] += bf2f(u2.y) * m2;
      acc[2 % VEC] += bf2f(u2.z) * m2; acc[3 % VEC] += bf2f(u2.w) * m2;
      acc[0] += bf2f(u3.x) * m3; acc[1] += bf2f(u3.y) * m3;
      acc[2 % VEC] += bf2f(u3.z) * m3; acc[3 % VEC] += bf2f(u3.w) * m3;
    } else {
      ushort2 u0 = *(const ushort2*)&hb[(size_t)s0 * DOUT + t * 2];
      ushort2 u1 = *(const ushort2*)&hb[(size_t)s1 * DOUT + t * 2];
      ushort2 u2 = *(const ushort2*)&hb[(size_t)s2 * DOUT + t * 2];
      ushort2 u3 = *(const ushort2*)&hb[(size_t)s3 * DOUT + t * 2];
      acc[0] += bf2f(u0.x) * m0; acc[1 % VEC] += bf2f(u0.y) * m0;
      acc[0] += bf2f(u1.x) * m1; acc[1 % VEC] += bf2f(u1.y) * m1;
      acc[0] += bf2f(u2.x) * m2; acc[1 % VEC] += bf2f(u2.y) * m2;
      acc[0] += bf2f(u3.x) * m3; acc[1 % VEC] += bf2f(u3.y) * m3;
    }
  }
  for (; i < end; ++i) {
    int s = csr_src[i];
    float nrm = norm1[i];
    if (VEC == 4) {
      ushort4 u = *(const ushort4*)&hb[(size_t)s * DOUT + t * 4];
      acc[0] += bf2f(u.x) * nrm; acc[1] += bf2f(u.y) * nrm;
      acc[2 % VEC] += bf2f(u.z) * nrm; acc[3 % VEC] += bf2f(u.w) * nrm;
    } else {
      ushort2 u = *(const ushort2*)&hb[(size_t)s * DOUT + t * 2];
      acc[0] += bf2f(u.x) * nrm; acc[1 % VEC] += bf2f(u.y) * nrm;
    }
  }
#pragma unroll
  for (int k = 0; k < VEC; ++k) {
    float r = acc[k] + bias[t * VEC + k];
    if (RELU) r = fmaxf(r, 0.0f);
    if (OMODE == 1) {
      ob[(size_t)d * DOUT + t * VEC + k] = bf16_rne(r);
    } else {
      out[(size_t)d * DOUT + t * VEC + k] = r;
    }
  }
}

// ---------------- pooling: per-graph sum + max (encoded uint) -----------------
__global__ __launch_bounds__(128)
void pool_kernel(const float* __restrict__ h3, const int* __restrict__ batch,
                 float* __restrict__ gsum, unsigned* __restrict__ gmax, int n) {
  int c = threadIdx.x;
  int start = blockIdx.x * 32;
  int end = min(start + 32, n);
  int curg = -1;
  float s = 0.0f, m = -3.402823466e38f;
  for (int i = start; i < end; ++i) {
    int g = batch[i];
    if (g != curg) {
      if (curg >= 0) {
        atomicAdd(&gsum[curg * 128 + c], s);
        atomicMax(&gmax[curg * 128 + c], fencode(m));
      }
      curg = g; s = 0.0f; m = -3.402823466e38f;
    }
    float v = h3[(size_t)i * 128 + c];
    s += v;
    m = fmaxf(m, v);
  }
  if (curg >= 0) {
    atomicAdd(&gsum[curg * 128 + c], s);
    atomicMax(&gmax[curg * 128 + c], fencode(m));
  }
}

// ---------------- final MLP; per-graph counts via binary search ---------------
__global__ __launch_bounds__(512)
void mlp_kernel(const float* __restrict__ gsum, const unsigned* __restrict__ gmax,
                const int* __restrict__ batch, int n, const float* __restrict__ Wm1,
                const float* __restrict__ bm1, const float* __restrict__ Wm2,
                const float* __restrict__ bm2, float* __restrict__ out) {
  __shared__ float hid[64][8];
  int t = threadIdx.x;
  int gi = t >> 3, u = t & 7;
  auto lb = [&](int key) {
    int lo = 0, hi = n;
    while (lo < hi) {
      int mid = (lo + hi) >> 1;
      if (batch[mid] < key) lo = mid + 1; else hi = mid;
    }
    return lo;
  };
  int cnt = lb(gi + 1) - lb(gi);
  float inv = 1.0f / fmaxf((float)cnt, 1.0f);
  float s = bm1[u];
  for (int k = 0; k < 128; ++k) {
    float mean = gsum[gi * 128 + k] * inv;
    s += mean * Wm1[k * 8 + u];
  }
  for (int k = 0; k < 128; ++k) {
    float mx = (cnt > 0) ? fdecode(gmax[gi * 128 + k]) : 0.0f;
    s += mx * Wm1[(128 + k) * 8 + u];
  }
  hid[gi][u] = fmaxf(s, 0.0f);
  __syncthreads();
  if (t < 128) {
    int g2 = t >> 1, o = t & 1;
    float s2 = bm2[o];
#pragma unroll
    for (int uu = 0; uu < 8; ++uu) s2 += hid[g2][uu] * Wm2[uu * 2 + o];
    out[g2 * 2 + o] = s2;
  }
}

extern "C" void kernel_launch(void* const* d_in, const int* in_sizes, int n_in,
                              void* d_out, int out_size, void* d_ws, size_t ws_size,
                              hipStream_t stream) {
  const float* x     = (const float*)d_in[0];
  const int*   ei    = (const int*)d_in[1];
  const float* eattr = (const float*)d_in[2];
  const int*   batch = (const int*)d_in[3];
  const float* W1A = (const float*)d_in[4],  *b1A = (const float*)d_in[5];
  const float* W1B = (const float*)d_in[6],  *b1B = (const float*)d_in[7];
  const float* W1C = (const float*)d_in[8],  *b1C = (const float*)d_in[9];
  const float* W1D = (const float*)d_in[10], *b1D = (const float*)d_in[11];
  const float* W2  = (const float*)d_in[12], *b2  = (const float*)d_in[13];
  const float* W3  = (const float*)d_in[14], *b3  = (const float*)d_in[15];
  const float* Wm1 = (const float*)d_in[16], *bm1 = (const float*)d_in[17];
  const float* Wm2 = (const float*)d_in[18], *bm2 = (const float*)d_in[19];
  float* out = (float*)d_out;

  const int n = in_sizes[0] / 128;
  const int E = in_sizes[1] / 2;
  const int npad = (n + 127) & ~127;
  const int nmb = npad / 128;

  char* ws = (char*)d_ws;
  size_t off = 0;
  auto alloc = [&](size_t bytes) -> void* {
    void* p = ws + off;
    off += (bytes + 255) & ~(size_t)255;
    return p;
  };

  float*    dis     = (float*)alloc((size_t)5 * n * 4);
  int*      rowptr  = (int*)alloc(((size_t)n + 1) * 4);
  int*      rowwork = (int*)alloc((size_t)n * 4);
  int*      local   = (int*)alloc((size_t)n * 4);
  int*      bsum    = (int*)alloc(256 * 4);
  // ---- zero block start ----
  size_t zoff = off;
  int*      cnt     = (int*)alloc((size_t)n * 4);
  float*    gsum    = (float*)alloc(64 * 128 * 4);
  unsigned* gmax    = (unsigned*)alloc(64 * 128 * 4);
  size_t zbytes = off - zoff;
  // ---- zero block end ----
  int*      csr_src = (int*)alloc((size_t)E * 4);
  int*      csr_dst = (int*)alloc((size_t)E * 4);
  float4*   csr_w   = (float4*)alloc((size_t)E * 16);
  float4*   norm4   = (float4*)alloc((size_t)E * 16);
  float*    norm1   = (float*)alloc((size_t)E * 4);
  unsigned short* W1t = (unsigned short*)alloc(65536 * 2);
  unsigned short* W2t = (unsigned short*)alloc(131072 * 2);
  unsigned short* W3t = (unsigned short*)alloc(32768 * 2);
  float*    biascat = (float*)alloc(512 * 4);
  unsigned short* xb   = (unsigned short*)alloc((size_t)npad * 128 * 2);
  unsigned short* bufA = (unsigned short*)alloc((size_t)npad * 512 * 2);  // xa / h2pre / h3pre
  unsigned short* bufB = (unsigned short*)alloc((size_t)npad * 512 * 2);  // h1 / h2+h3
  alloc(4096);  // guard pad

  unsigned short* xa      = bufA;                     // 4 planes [npad,128] bf16
  unsigned short* h1      = bufB;                     // [npad,512] bf16
  unsigned short* h2pre_b = bufA;                     // [npad,256] bf16 (xa dead)
  unsigned short* h2      = bufB;                     // [npad,256] bf16 (h1 dead after gemm_l2)
  unsigned short* h3pre_b = bufA;                     // [npad,128] bf16 (h2pre dead)
  float*          h3      = (float*)(bufB + (size_t)npad * 256);  // [npad,128] fp32

  hipMemsetAsync(ws + zoff, 0, zbytes, stream);

  int total4 = n * 32;
  prep_kernel<<<(total4 + 255) / 256, 256, 0, stream>>>(
      W1A, W1B, W1C, W1D, b1A, b1B, b1C, b1D, W2, W3,
      W1t, W2t, W3t, biascat, x, xb, total4);

  int nb = (n + 255) / 256;
  hist_kernel<<<(E + 255) / 256, 256, 0, stream>>>(ei, cnt, E);
  scan1_kernel<<<nb, 256, 0, stream>>>(cnt, local, bsum, n);
  scan2_kernel<<<1, 256, 0, stream>>>(bsum, nb);
  scan3_kernel<<<nb, 256, 0, stream>>>(local, bsum, rowptr, rowwork, n, E);
  fill_kernel<<<(E + 255) / 256, 256, 0, stream>>>(ei, eattr, rowwork, csr_src, csr_dst, csr_w, E);
  degcsr_kernel<<<(n + 255) / 256, 256, 0, stream>>>(rowptr, csr_w, dis, n);
  edgeprep_kernel<<<(E + 255) / 256, 256, 0, stream>>>(csr_src, csr_dst, csr_w,
                                                       dis, norm4, norm1, n, E);

  int nodeblk = (n + 3) / 4;
  // layer 1
  agg4x_kernel<<<nodeblk, 256, 0, stream>>>(xb, xa, rowptr, csr_src, norm4, dis, n, npad);
  gemm_l1_mfma<<<dim3(nmb, 1, 4), 256, 0, stream>>>(xa, W1t, biascat, h1, n, npad);
  // layer 2
  gemm_l2_wide<<<nmb, 512, 0, stream>>>(h1, W2t, h2pre_b, n);
  agg1_kernel<4, true, 1><<<nodeblk, 256, 0, stream>>>(h2pre_b, nullptr, h2,
                                                       rowptr, csr_src, norm1,
                                                       dis + (size_t)4 * n, b2, n);
  // layer 3
  gemm_bf16out<<<dim3(nmb, 1), 256, 0, stream>>>(h2, 256, W3t, h3pre_b, 128, n);
  agg1_kernel<2, false, 0><<<nodeblk, 256, 0, stream>>>(h3pre_b, h3, nullptr,
                                                        rowptr, csr_src, norm1,
                                                        dis + (size_t)4 * n, b3, n);

  pool_kernel<<<(n + 31) / 32, 128, 0, stream>>>(h3, batch, gsum, gmax, n);
  mlp_kernel<<<1, 512, 0, stream>>>(gsum, gmax, batch, n, Wm1, bm1, Wm2, bm2, out);
}